// Round 9
// baseline (281.557 us; speedup 1.0000x reference)
//
#include <hip/hip_runtime.h>

// QattenNet: B=E*T=8192, S=256, A=32, O=128, QH1=128, QD=64, C1=128, H=4.
// R12: memory model: harness poison fills leave L3 (256MB) dirty; our 134MB
// fs stream misses L3 everywhere and pays dirty-eviction writebacks (~256MB,
// invisible to TCC counters) -> stream wall ~62-78us regardless of kernel
// shape (R3..R11). Controllable: final kernel (4.4us + 16MB g/v round-trip)
// and R10's 1.5-generation tail (1536 blocks @4/CU; tail = pure stream).
// Design: wave-specialized single block. 512 thr x 512 blocks = exactly one
// generation at 2 blocks/CU. Waves 0-3 stream the block's own 16 rows into
// g_lds (16-deep reg batches); waves 4-7 run the MLP. Barriers: {issue batch0
// / stage s} -> sync1 -> {stream rest || phase2} -> sync2 -> phase3 -> sync3
// -> phase4 + dot(g_lds) + bias -> out. Unlike R11 (serial stream->MLP,
// 106us), only the ~3us phases 3-4 trail the stream.

static constexpr int Sd  = 256;
static constexpr int Ad  = 32;
static constexpr int Od  = 128;
static constexpr int QDd = 64;
static constexpr int NB  = 16;
static constexpr int NBLK = 512;        // 8192 / NB; 2 blocks/CU exactly

__global__ void qatten_prep(const float* __restrict__ Wk, const float* __restrict__ bk,
                            float* __restrict__ WkT, float* __restrict__ bkSum)
{
    int idx = blockIdx.x * 256 + threadIdx.x;   // 0..8191
    int k = idx >> 7;          // 0..63
    int o = idx & 127;         // 0..127
    float s = 0.f;
#pragma unroll
    for (int h = 0; h < 4; ++h) s += Wk[h * (Od * QDd) + o * QDd + k];
    WkT[k * Od + o] = s;
    if (idx < QDd) {
        float t = 0.f;
#pragma unroll
        for (int h = 0; h < 4; ++h) t += bk[h * QDd + idx];
        bkSum[idx] = t;
    }
}

__global__ __launch_bounds__(512, 4) void qatten_fused(
    const float* __restrict__ qv, const float* __restrict__ st, const float* __restrict__ fs,
    const float* __restrict__ Wq1, const float* __restrict__ bq1,
    const float* __restrict__ Wq2, const float* __restrict__ bq2,
    const float* __restrict__ Wc1, const float* __restrict__ bc1,
    const float* __restrict__ Wc2, const float* __restrict__ bc2,
    const float* __restrict__ WkT, const float* __restrict__ bkSum,
    float* __restrict__ out)
{
    __shared__ float s_lds[NB][Sd];     // 16 KB
    __shared__ float h_lds[NB][260];    // 16.25 KB (cols 0-127: h1, 128-255: hc)
    __shared__ float emb_lds[NB][68];   // 4.25 KB
    __shared__ float g_lds[NB][128];    // 8 KB     total ~44.5 KB -> 2 blocks/CU

    const int tid = threadIdx.x;
    const int b0 = blockIdx.x * NB;
    const bool streamer = (tid < 256);          // waves 0-3
    const int l = tid & 63;

    // streamer state that must live across sync1
    float4 x0a[8], x1a[8];
    float q0p0 = 0.f, q1p0 = 0.f, q0p1 = 0.f, q1p1 = 0.f;
    const float4* f0p0 = nullptr;

    if (streamer) {
        // wave w handles rows b0+4w .. b0+4w+3 as two pairs.
        const int w = tid >> 6;                 // 0..3
        const int rA0 = b0 + 4 * w;             // pair0 rows rA0, rA0+1
        f0p0 = (const float4*)fs + (size_t)rA0 * (Ad * Od / 4);
        q0p0 = qv[(size_t)rA0 * Ad + (l & 31)];
        q1p0 = qv[(size_t)(rA0 + 1) * Ad + (l & 31)];
        q0p1 = qv[(size_t)(rA0 + 2) * Ad + (l & 31)];
        q1p1 = qv[(size_t)(rA0 + 3) * Ad + (l & 31)];
        // issue pair0 batch0: 16 loads in flight before the barrier
        const float4* __restrict__ f1 = f0p0 + (Ad * Od / 4);
#pragma unroll
        for (int i = 0; i < 8; ++i) {
            x0a[i] = f0p0[i * 64 + l];
            x1a[i] = f1[i * 64 + l];
        }
    } else {
        // MLP waves: stage s (16x256 = 1024 float4 over 256 threads)
        const int t = tid - 256;
        const float4* sp = (const float4*)(st + (size_t)b0 * Sd);
        float4* sl = (float4*)&s_lds[0][0];
        sl[t]       = sp[t];
        sl[t + 256] = sp[t + 256];
        sl[t + 512] = sp[t + 512];
        sl[t + 768] = sp[t + 768];
    }
    __syncthreads();    // sync1: s ready; streamer batch0 landed

    if (streamer) {
        // ---- full stream: pair0 (batch0 in regs, batch1), pair1 (2 batches) ----
        const int w = tid >> 6;
        const float4* __restrict__ f0 = f0p0;
        const float4* __restrict__ f1 = f0 + (Ad * Od / 4);
        float4 a0 = {0.f, 0.f, 0.f, 0.f}, a1 = {0.f, 0.f, 0.f, 0.f};
        // pair0 batch0 consume (chunks 0..7)
#pragma unroll
        for (int i = 0; i < 8; ++i) {
            const float qa0 = __shfl(q0p0, 2 * i + (l >> 5), 64);
            const float qa1 = __shfl(q1p0, 2 * i + (l >> 5), 64);
            a0.x = fmaf(qa0, x0a[i].x, a0.x);
            a0.y = fmaf(qa0, x0a[i].y, a0.y);
            a0.z = fmaf(qa0, x0a[i].z, a0.z);
            a0.w = fmaf(qa0, x0a[i].w, a0.w);
            a1.x = fmaf(qa1, x1a[i].x, a1.x);
            a1.y = fmaf(qa1, x1a[i].y, a1.y);
            a1.z = fmaf(qa1, x1a[i].z, a1.z);
            a1.w = fmaf(qa1, x1a[i].w, a1.w);
        }
        // pair0 batch1 (chunks 8..15)
        {
            float4 x0[8], x1[8];
#pragma unroll
            for (int i = 0; i < 8; ++i) {
                x0[i] = f0[(8 + i) * 64 + l];
                x1[i] = f1[(8 + i) * 64 + l];
            }
#pragma unroll
            for (int i = 0; i < 8; ++i) {
                const int ii = 8 + i;
                const float qa0 = __shfl(q0p0, 2 * ii + (l >> 5), 64);
                const float qa1 = __shfl(q1p0, 2 * ii + (l >> 5), 64);
                a0.x = fmaf(qa0, x0[i].x, a0.x);
                a0.y = fmaf(qa0, x0[i].y, a0.y);
                a0.z = fmaf(qa0, x0[i].z, a0.z);
                a0.w = fmaf(qa0, x0[i].w, a0.w);
                a1.x = fmaf(qa1, x1[i].x, a1.x);
                a1.y = fmaf(qa1, x1[i].y, a1.y);
                a1.z = fmaf(qa1, x1[i].z, a1.z);
                a1.w = fmaf(qa1, x1[i].w, a1.w);
            }
        }
        a0.x += __shfl_xor(a0.x, 32, 64);
        a0.y += __shfl_xor(a0.y, 32, 64);
        a0.z += __shfl_xor(a0.z, 32, 64);
        a0.w += __shfl_xor(a0.w, 32, 64);
        a1.x += __shfl_xor(a1.x, 32, 64);
        a1.y += __shfl_xor(a1.y, 32, 64);
        a1.z += __shfl_xor(a1.z, 32, 64);
        a1.w += __shfl_xor(a1.w, 32, 64);
        if (l < 32) {
            *(float4*)&g_lds[4 * w][l * 4]     = a0;
            *(float4*)&g_lds[4 * w + 1][l * 4] = a1;
        }
        // pair1: rows rA0+2, rA0+3
        const float4* __restrict__ g0 = f0 + 2 * (Ad * Od / 4);
        const float4* __restrict__ g1 = f0 + 3 * (Ad * Od / 4);
        float4 b0v = {0.f, 0.f, 0.f, 0.f}, b1v = {0.f, 0.f, 0.f, 0.f};
#pragma unroll
        for (int batch = 0; batch < 2; ++batch) {
            float4 x0[8], x1[8];
#pragma unroll
            for (int i = 0; i < 8; ++i) {
                x0[i] = g0[(batch * 8 + i) * 64 + l];
                x1[i] = g1[(batch * 8 + i) * 64 + l];
            }
#pragma unroll
            for (int i = 0; i < 8; ++i) {
                const int ii = batch * 8 + i;
                const float qa0 = __shfl(q0p1, 2 * ii + (l >> 5), 64);
                const float qa1 = __shfl(q1p1, 2 * ii + (l >> 5), 64);
                b0v.x = fmaf(qa0, x0[i].x, b0v.x);
                b0v.y = fmaf(qa0, x0[i].y, b0v.y);
                b0v.z = fmaf(qa0, x0[i].z, b0v.z);
                b0v.w = fmaf(qa0, x0[i].w, b0v.w);
                b1v.x = fmaf(qa1, x1[i].x, b1v.x);
                b1v.y = fmaf(qa1, x1[i].y, b1v.y);
                b1v.z = fmaf(qa1, x1[i].z, b1v.z);
                b1v.w = fmaf(qa1, x1[i].w, b1v.w);
            }
        }
        b0v.x += __shfl_xor(b0v.x, 32, 64);
        b0v.y += __shfl_xor(b0v.y, 32, 64);
        b0v.z += __shfl_xor(b0v.z, 32, 64);
        b0v.w += __shfl_xor(b0v.w, 32, 64);
        b1v.x += __shfl_xor(b1v.x, 32, 64);
        b1v.y += __shfl_xor(b1v.y, 32, 64);
        b1v.z += __shfl_xor(b1v.z, 32, 64);
        b1v.w += __shfl_xor(b1v.w, 32, 64);
        if (l < 32) {
            *(float4*)&g_lds[4 * w + 2][l * 4] = b0v;
            *(float4*)&g_lds[4 * w + 3][l * 4] = b1v;
        }
    } else {
        // ---- phase 2: h = relu(s @ [Wq1|Wc1] + [bq1|bc1]); 4 rows x 4 cols ----
        const int t = tid - 256;
        const int wg = t & 63;                 // col group: cols 4wg..4wg+3
        const int rg = (t >> 6) << 2;          // row base: 0,4,8,12
        const float* __restrict__ Wb = (wg < 32) ? (Wq1 + 4 * wg)
                                                 : (Wc1 + 4 * (wg - 32));
        const float4 bb4 = (wg < 32) ? *(const float4*)&bq1[4 * wg]
                                     : *(const float4*)&bc1[4 * (wg - 32)];
        float acc[4][4];
#pragma unroll
        for (int r = 0; r < 4; ++r)
#pragma unroll
            for (int c = 0; c < 4; ++c) acc[r][c] = 0.f;

        for (int k = 0; k < Sd; k += 4) {
            float w[4][4], sv[4][4];
#pragma unroll
            for (int kk = 0; kk < 4; ++kk) {
                const float4 tt = *(const float4*)&Wb[(size_t)(k + kk) * 128];
                w[kk][0] = tt.x; w[kk][1] = tt.y; w[kk][2] = tt.z; w[kk][3] = tt.w;
            }
#pragma unroll
            for (int r = 0; r < 4; ++r) {
                const float4 tt = *(const float4*)&s_lds[rg + r][k];
                sv[r][0] = tt.x; sv[r][1] = tt.y; sv[r][2] = tt.z; sv[r][3] = tt.w;
            }
#pragma unroll
            for (int r = 0; r < 4; ++r)
#pragma unroll
                for (int kk = 0; kk < 4; ++kk)
#pragma unroll
                    for (int c = 0; c < 4; ++c)
                        acc[r][c] = fmaf(sv[r][kk], w[kk][c], acc[r][c]);
        }
#pragma unroll
        for (int r = 0; r < 4; ++r) {
            float4 o;
            o.x = fmaxf(acc[r][0] + bb4.x, 0.f);
            o.y = fmaxf(acc[r][1] + bb4.y, 0.f);
            o.z = fmaxf(acc[r][2] + bb4.z, 0.f);
            o.w = fmaxf(acc[r][3] + bb4.w, 0.f);
            *(float4*)&h_lds[rg + r][4 * wg] = o;
        }
    }
    __syncthreads();    // sync2: h ready, g ready

    if (!streamer) {
        // ---- phase 3: emb = h1 @ Wq2 + bq2; thread = 1 row x 4 cols ----
        const int t = tid - 256;
        const int cg = t & 15;          // cols 4cg..4cg+3 (of 64)
        const int row = t >> 4;         // 0..15
        float acc[4] = {0.f, 0.f, 0.f, 0.f};
        for (int k = 0; k < 128; k += 4) {
            float w[4][4];
#pragma unroll
            for (int kk = 0; kk < 4; ++kk) {
                const float4 tt = *(const float4*)&Wq2[(size_t)(k + kk) * 64 + 4 * cg];
                w[kk][0] = tt.x; w[kk][1] = tt.y; w[kk][2] = tt.z; w[kk][3] = tt.w;
            }
            const float4 h4 = *(const float4*)&h_lds[row][k];
#pragma unroll
            for (int c = 0; c < 4; ++c) {
                float a = acc[c];
                a = fmaf(h4.x, w[0][c], a);
                a = fmaf(h4.y, w[1][c], a);
                a = fmaf(h4.z, w[2][c], a);
                a = fmaf(h4.w, w[3][c], a);
                acc[c] = a;
            }
        }
        const float4 b4 = *(const float4*)&bq2[4 * cg];
        float4 o;
        o.x = acc[0] + b4.x; o.y = acc[1] + b4.y;
        o.z = acc[2] + b4.z; o.w = acc[3] + b4.w;
        *(float4*)&emb_lds[row][4 * cg] = o;
    }
    __syncthreads();    // sync3: emb ready

    if (!streamer) {
        // ---- phase 4 + fused epilogue: v in regs, dot g_lds, bias -> out ----
        // thread = 2 rows x 4 cols of v; 32 lanes per row reduce.
        const int t = tid - 256;
        const int cg = t & 31;              // v cols 4cg..4cg+3 (of 128)
        const int rp = (t >> 5) << 1;       // rows rp, rp+1
        float acc[2][4];
#pragma unroll
        for (int r = 0; r < 2; ++r)
#pragma unroll
            for (int c = 0; c < 4; ++c) acc[r][c] = 0.f;
        for (int k = 0; k < QDd; k += 4) {
            float w[4][4], ev[2][4];
#pragma unroll
            for (int kk = 0; kk < 4; ++kk) {
                const float4 tt = *(const float4*)&WkT[(size_t)(k + kk) * 128 + 4 * cg];
                w[kk][0] = tt.x; w[kk][1] = tt.y; w[kk][2] = tt.z; w[kk][3] = tt.w;
            }
#pragma unroll
            for (int r = 0; r < 2; ++r) {
                const float4 tt = *(const float4*)&emb_lds[rp + r][k];
                ev[r][0] = tt.x; ev[r][1] = tt.y; ev[r][2] = tt.z; ev[r][3] = tt.w;
            }
#pragma unroll
            for (int r = 0; r < 2; ++r)
#pragma unroll
                for (int kk = 0; kk < 4; ++kk)
#pragma unroll
                    for (int c = 0; c < 4; ++c)
                        acc[r][c] = fmaf(ev[r][kk], w[kk][c], acc[r][c]);
        }
#pragma unroll
        for (int r = 0; r < 2; ++r) {
            const int row = rp + r;
            const int b = b0 + row;
            const float4 g4 = *(const float4*)&g_lds[row][4 * cg];
            float d = acc[r][0] * g4.x;
            d = fmaf(acc[r][1], g4.y, d);
            d = fmaf(acc[r][2], g4.z, d);
            d = fmaf(acc[r][3], g4.w, d);
            float pb = fmaf(emb_lds[row][cg],      bkSum[cg],      0.f);
            pb       = fmaf(emb_lds[row][cg + 32], bkSum[cg + 32], pb);
            float pc = 0.f;
#pragma unroll
            for (int j = 0; j < 4; ++j)
                pc = fmaf(h_lds[row][128 + cg + 32 * j], Wc2[cg + 32 * j], pc);
            float pq = qv[(size_t)b * Ad + cg];
#pragma unroll
            for (int dd = 16; dd >= 1; dd >>= 1) {
                d  += __shfl_down(d,  dd, 32);
                pb += __shfl_down(pb, dd, 32);
                pc += __shfl_down(pc, dd, 32);
                pq += __shfl_down(pq, dd, 32);
            }
            if (cg == 0)
                out[b] = d + (pc + bc2[0]) + pb * pq;
        }
    }
}

extern "C" void kernel_launch(void* const* d_in, const int* in_sizes, int n_in,
                              void* d_out, int out_size, void* d_ws, size_t ws_size,
                              hipStream_t stream) {
    const float* qv  = (const float*)d_in[0];
    const float* st  = (const float*)d_in[1];
    const float* fs  = (const float*)d_in[2];
    const float* Wq1 = (const float*)d_in[3];
    const float* bq1 = (const float*)d_in[4];
    const float* Wq2 = (const float*)d_in[5];
    const float* bq2 = (const float*)d_in[6];
    const float* Wk  = (const float*)d_in[7];
    const float* bk  = (const float*)d_in[8];
    const float* Wc1 = (const float*)d_in[9];
    const float* bc1 = (const float*)d_in[10];
    const float* Wc2 = (const float*)d_in[11];
    const float* bc2 = (const float*)d_in[12];
    float* out = (float*)d_out;

    // workspace (floats): WkT 8192 | bkSum 64   (33 KB)
    float* WkT   = (float*)d_ws;
    float* bkSum = WkT + QDd * Od;          // +8192

    qatten_prep<<<32, 256, 0, stream>>>(Wk, bk, WkT, bkSum);
    qatten_fused<<<NBLK, 512, 0, stream>>>(qv, st, fs, Wq1, bq1, Wq2, bq2,
                                           Wc1, bc1, Wc2, bc2, WkT, bkSum, out);
}

// Round 10
// 243.159 us; speedup vs baseline: 1.1579x; 1.1579x over previous
//
#include <hip/hip_runtime.h>

// QattenNet: B=E*T=8192, S=256, A=32, O=128, QH1=128, QD=64, C1=128, H=4.
// R13: R12's WRITE_SIZE=115MB exposed register SPILLS (launch_bounds(512,4)
// => 64-VGPR cap vs 16 live float4 in the streamer) — every fs byte detoured
// through scratch, yet the kernel still hit 2 TB/s (2x R10). Keep the
// wave-specialized structure, remove the spill and the barriers:
//  - __launch_bounds__(512) only: compiler free (~100 VGPR), natural 2 blk/CU
//    (44.5 KB LDS). No state held across barriers except 8 v-accumulators.
//  - Row-aligned ownership: streamer wave w produces g rows 4w..4w+3; MLP
//    wave m (=w-4) stages/computes rows 4m..4m+3 through ALL phases (stage,
//    h, emb, v) with zero cross-wave deps. Single top-level __syncthreads
//    (g_lds handoff), then per-wave epilogue -> out. One kernel, one barrier.
//  - Streamer inner loop = R10's proven no-spill code (2 batches of 8x2
//    float4), run for 2 row-pairs.

static constexpr int Sd  = 256;
static constexpr int Ad  = 32;
static constexpr int Od  = 128;
static constexpr int QDd = 64;
static constexpr int NB  = 16;
static constexpr int NBLK = 512;        // 8192 / NB

__global__ void qatten_prep(const float* __restrict__ Wk, const float* __restrict__ bk,
                            float* __restrict__ WkT, float* __restrict__ bkSum)
{
    int idx = blockIdx.x * 256 + threadIdx.x;   // 0..8191
    int k = idx >> 7;          // 0..63
    int o = idx & 127;         // 0..127
    float s = 0.f;
#pragma unroll
    for (int h = 0; h < 4; ++h) s += Wk[h * (Od * QDd) + o * QDd + k];
    WkT[k * Od + o] = s;
    if (idx < QDd) {
        float t = 0.f;
#pragma unroll
        for (int h = 0; h < 4; ++h) t += bk[h * QDd + idx];
        bkSum[idx] = t;
    }
}

__global__ __launch_bounds__(512) void qatten_fused(
    const float* __restrict__ qv, const float* __restrict__ st, const float* __restrict__ fs,
    const float* __restrict__ Wq1, const float* __restrict__ bq1,
    const float* __restrict__ Wq2, const float* __restrict__ bq2,
    const float* __restrict__ Wc1, const float* __restrict__ bc1,
    const float* __restrict__ Wc2, const float* __restrict__ bc2,
    const float* __restrict__ WkT, const float* __restrict__ bkSum,
    float* __restrict__ out)
{
    __shared__ float s_lds[NB][Sd];     // 16 KB
    __shared__ float h_lds[NB][260];    // 16.25 KB (h1 at 4l<128, hc at 4l>=128)
    __shared__ float emb_lds[NB][68];   // 4.25 KB
    __shared__ float g_lds[NB][128];    // 8 KB     total ~44.5 KB -> 2 blocks/CU

    const int tid  = threadIdx.x;
    const int wave = tid >> 6;          // 0..7
    const int l    = tid & 63;
    const int b0   = blockIdx.x * NB;

    float vreg[4][2];                   // v[row r][col l, l+64] across the barrier

    if (wave < 4) {
        // ============ streamer wave w: g rows b0+4w..+3 -> g_lds ============
        const int r0 = b0 + 4 * wave;
#pragma unroll
        for (int p = 0; p < 2; ++p) {
            const int ra = r0 + 2 * p;
            const float4* __restrict__ f0 = (const float4*)fs + (size_t)ra * (Ad * Od / 4);
            const float4* __restrict__ f1 = f0 + (Ad * Od / 4);
            const float q0 = qv[(size_t)ra * Ad + (l & 31)];
            const float q1 = qv[(size_t)(ra + 1) * Ad + (l & 31)];
            float4 a0 = {0.f, 0.f, 0.f, 0.f}, a1 = {0.f, 0.f, 0.f, 0.f};
#pragma unroll
            for (int batch = 0; batch < 2; ++batch) {
                float4 x0[8], x1[8];
#pragma unroll
                for (int i = 0; i < 8; ++i) {
                    x0[i] = f0[(batch * 8 + i) * 64 + l];
                    x1[i] = f1[(batch * 8 + i) * 64 + l];
                }
#pragma unroll
                for (int i = 0; i < 8; ++i) {
                    const int ii = batch * 8 + i;
                    const float qa0 = __shfl(q0, 2 * ii + (l >> 5), 64);
                    const float qa1 = __shfl(q1, 2 * ii + (l >> 5), 64);
                    a0.x = fmaf(qa0, x0[i].x, a0.x);
                    a0.y = fmaf(qa0, x0[i].y, a0.y);
                    a0.z = fmaf(qa0, x0[i].z, a0.z);
                    a0.w = fmaf(qa0, x0[i].w, a0.w);
                    a1.x = fmaf(qa1, x1[i].x, a1.x);
                    a1.y = fmaf(qa1, x1[i].y, a1.y);
                    a1.z = fmaf(qa1, x1[i].z, a1.z);
                    a1.w = fmaf(qa1, x1[i].w, a1.w);
                }
            }
            a0.x += __shfl_xor(a0.x, 32, 64);
            a0.y += __shfl_xor(a0.y, 32, 64);
            a0.z += __shfl_xor(a0.z, 32, 64);
            a0.w += __shfl_xor(a0.w, 32, 64);
            a1.x += __shfl_xor(a1.x, 32, 64);
            a1.y += __shfl_xor(a1.y, 32, 64);
            a1.z += __shfl_xor(a1.z, 32, 64);
            a1.w += __shfl_xor(a1.w, 32, 64);
            if (l < 32) {
                *(float4*)&g_lds[4 * wave + 2 * p][l * 4]     = a0;
                *(float4*)&g_lds[4 * wave + 2 * p + 1][l * 4] = a1;
            }
        }
    } else {
        // ============ MLP wave m: rows lr..lr+3 through all phases ============
        const int m  = wave - 4;        // 0..3
        const int lr = 4 * m;           // local row base

        // ---- stage own 4 rows of s (4 float4 per lane, coalesced) ----
        {
            const float4* sp = (const float4*)(st + (size_t)(b0 + lr) * Sd);
            float4* sl = (float4*)&s_lds[lr][0];
#pragma unroll
            for (int i = 0; i < 4; ++i) sl[l + 64 * i] = sp[l + 64 * i];
        }

        // ---- phase 2: h[lr+r][4l..4l+3] = relu(s @ [Wq1|Wc1] + bias) ----
        // lane l<32 -> Wq1 cols 4l..4l+3 (h cols 4l), l>=32 -> Wc1 cols
        // 4(l-32).. (h cols 128+4(l-32) = 4l). Store addr = 4l either way.
        {
            const float* __restrict__ Wb = (l < 32) ? (Wq1 + 4 * l)
                                                    : (Wc1 + 4 * (l - 32));
            const float4 bb4 = (l < 32) ? *(const float4*)&bq1[4 * l]
                                        : *(const float4*)&bc1[4 * (l - 32)];
            float acc[4][4];
#pragma unroll
            for (int r = 0; r < 4; ++r)
#pragma unroll
                for (int c = 0; c < 4; ++c) acc[r][c] = 0.f;

            for (int k = 0; k < Sd; k += 4) {
                float w[4][4];
#pragma unroll
                for (int kk = 0; kk < 4; ++kk) {
                    const float4 t = *(const float4*)&Wb[(size_t)(k + kk) * 128];
                    w[kk][0] = t.x; w[kk][1] = t.y; w[kk][2] = t.z; w[kk][3] = t.w;
                }
#pragma unroll
                for (int r = 0; r < 4; ++r) {
                    const float4 s4 = *(const float4*)&s_lds[lr + r][k];
                    float a0 = acc[r][0], a1 = acc[r][1], a2 = acc[r][2], a3 = acc[r][3];
                    a0 = fmaf(s4.x, w[0][0], a0); a1 = fmaf(s4.x, w[0][1], a1);
                    a2 = fmaf(s4.x, w[0][2], a2); a3 = fmaf(s4.x, w[0][3], a3);
                    a0 = fmaf(s4.y, w[1][0], a0); a1 = fmaf(s4.y, w[1][1], a1);
                    a2 = fmaf(s4.y, w[1][2], a2); a3 = fmaf(s4.y, w[1][3], a3);
                    a0 = fmaf(s4.z, w[2][0], a0); a1 = fmaf(s4.z, w[2][1], a1);
                    a2 = fmaf(s4.z, w[2][2], a2); a3 = fmaf(s4.z, w[2][3], a3);
                    a0 = fmaf(s4.w, w[3][0], a0); a1 = fmaf(s4.w, w[3][1], a1);
                    a2 = fmaf(s4.w, w[3][2], a2); a3 = fmaf(s4.w, w[3][3], a3);
                    acc[r][0] = a0; acc[r][1] = a1; acc[r][2] = a2; acc[r][3] = a3;
                }
            }
#pragma unroll
            for (int r = 0; r < 4; ++r) {
                float4 o;
                o.x = fmaxf(acc[r][0] + bb4.x, 0.f);
                o.y = fmaxf(acc[r][1] + bb4.y, 0.f);
                o.z = fmaxf(acc[r][2] + bb4.z, 0.f);
                o.w = fmaxf(acc[r][3] + bb4.w, 0.f);
                *(float4*)&h_lds[lr + r][4 * l] = o;
            }
        }

        // ---- phase 3: emb[lr+r][l] = h1[lr+r] . Wq2[:,l] + bq2[l] ----
        {
            float e[4] = {0.f, 0.f, 0.f, 0.f};
            for (int k = 0; k < 128; k += 4) {
                const float w0 = Wq2[(size_t)(k + 0) * 64 + l];
                const float w1 = Wq2[(size_t)(k + 1) * 64 + l];
                const float w2 = Wq2[(size_t)(k + 2) * 64 + l];
                const float w3 = Wq2[(size_t)(k + 3) * 64 + l];
#pragma unroll
                for (int r = 0; r < 4; ++r) {
                    const float4 h4 = *(const float4*)&h_lds[lr + r][k];
                    float a = e[r];
                    a = fmaf(h4.x, w0, a);
                    a = fmaf(h4.y, w1, a);
                    a = fmaf(h4.z, w2, a);
                    a = fmaf(h4.w, w3, a);
                    e[r] = a;
                }
            }
            const float bq = bq2[l];
#pragma unroll
            for (int r = 0; r < 4; ++r) emb_lds[lr + r][l] = e[r] + bq;
        }

        // ---- phase 4: v[lr+r][l], v[lr+r][l+64] accumulated in vreg ----
        {
#pragma unroll
            for (int r = 0; r < 4; ++r) { vreg[r][0] = 0.f; vreg[r][1] = 0.f; }
            for (int k = 0; k < QDd; k += 4) {
                float wA[4], wB[4];
#pragma unroll
                for (int kk = 0; kk < 4; ++kk) {
                    wA[kk] = WkT[(size_t)(k + kk) * 128 + l];
                    wB[kk] = WkT[(size_t)(k + kk) * 128 + 64 + l];
                }
#pragma unroll
                for (int r = 0; r < 4; ++r) {
                    const float4 e4 = *(const float4*)&emb_lds[lr + r][k];
                    float a = vreg[r][0], b = vreg[r][1];
                    a = fmaf(e4.x, wA[0], a);  b = fmaf(e4.x, wB[0], b);
                    a = fmaf(e4.y, wA[1], a);  b = fmaf(e4.y, wB[1], b);
                    a = fmaf(e4.z, wA[2], a);  b = fmaf(e4.z, wB[2], b);
                    a = fmaf(e4.w, wA[3], a);  b = fmaf(e4.w, wB[3], b);
                    vreg[r][0] = a; vreg[r][1] = b;
                }
            }
        }
    }

    __syncthreads();    // single barrier: g_lds handoff (streamer w -> MLP w)

    if (wave >= 4) {
        // ---- epilogue per row: out = g.v + (hc.Wc2 + bc2) + (emb.bkSum)*sumq ----
        const int lr = 4 * (wave - 4);
        const float wc2a = Wc2[l], wc2b = Wc2[l + 64];
        const float bks  = bkSum[l];
#pragma unroll
        for (int r = 0; r < 4; ++r) {
            const int row = lr + r;
            const int b   = b0 + row;
            float e = vreg[r][0] * g_lds[row][l];
            e = fmaf(vreg[r][1], g_lds[row][l + 64], e);
            e = fmaf(h_lds[row][128 + l], wc2a, e);
            e = fmaf(h_lds[row][192 + l], wc2b, e);
            float pb = emb_lds[row][l] * bks;
            float pq = (l < 32) ? qv[(size_t)b * Ad + l] : 0.f;
#pragma unroll
            for (int d = 32; d >= 1; d >>= 1) {
                e  += __shfl_xor(e,  d, 64);
                pb += __shfl_xor(pb, d, 64);
                pq += __shfl_xor(pq, d, 64);
            }
            if (l == 0) out[b] = e + bc2[0] + pb * pq;
        }
    }
}

extern "C" void kernel_launch(void* const* d_in, const int* in_sizes, int n_in,
                              void* d_out, int out_size, void* d_ws, size_t ws_size,
                              hipStream_t stream) {
    const float* qv  = (const float*)d_in[0];
    const float* st  = (const float*)d_in[1];
    const float* fs  = (const float*)d_in[2];
    const float* Wq1 = (const float*)d_in[3];
    const float* bq1 = (const float*)d_in[4];
    const float* Wq2 = (const float*)d_in[5];
    const float* bq2 = (const float*)d_in[6];
    const float* Wk  = (const float*)d_in[7];
    const float* bk  = (const float*)d_in[8];
    const float* Wc1 = (const float*)d_in[9];
    const float* bc1 = (const float*)d_in[10];
    const float* Wc2 = (const float*)d_in[11];
    const float* bc2 = (const float*)d_in[12];
    float* out = (float*)d_out;

    // workspace (floats): WkT 8192 | bkSum 64   (33 KB)
    float* WkT   = (float*)d_ws;
    float* bkSum = WkT + QDd * Od;          // +8192

    qatten_prep<<<32, 256, 0, stream>>>(Wk, bk, WkT, bkSum);
    qatten_fused<<<NBLK, 512, 0, stream>>>(qv, st, fs, Wq1, bq1, Wq2, bq2,
                                           Wc1, bc1, Wc2, bc2, WkT, bkSum, out);
}